// Round 11
// baseline (88.317 us; speedup 1.0000x reference)
//
#include <hip/hip_runtime.h>

#define TOKENS 16384
#define HDIM   4096
#define NPARTS 8
#define KPW    (HDIM / NPARTS)      // 512 k per K-part
#define NCHK   (KPW / 64)           // 8 chunks of 64 k per part
#define CHU    1536                 // int4 units per chunk (2ksub x 4nt x 3pl x 64)

typedef __attribute__((ext_vector_type(8))) short bf16x8;
typedef __attribute__((ext_vector_type(4))) float f32x4;

union PKU { unsigned int u[4]; int4 i4; bf16x8 v; };

__device__ __forceinline__ float4 L(const float* p) {
  return *reinterpret_cast<const float4*>(p);
}

// Exact 3-way bf16 split of 8 fp32: x = h + m + l (+O(2^-27) truncation)
__device__ __forceinline__ void split8(const float4 a, const float4 b,
                                       int4& h4, int4& m4, int4& l4) {
  const float e[8] = {a.x, a.y, a.z, a.w, b.x, b.y, b.z, b.w};
  unsigned int hb[8], mb[8], lb[8];
#pragma unroll
  for (int i = 0; i < 8; ++i) {
    const unsigned int xb = __float_as_uint(e[i]);
    hb[i] = xb & 0xFFFF0000u;
    const float r = e[i] - __uint_as_float(hb[i]);
    const unsigned int rb = __float_as_uint(r);
    mb[i] = rb & 0xFFFF0000u;
    const float r2 = r - __uint_as_float(mb[i]);
    lb[i] = __float_as_uint(r2);
  }
  PKU h, m, l;
#pragma unroll
  for (int j = 0; j < 4; ++j) {
    h.u[j] = (hb[2*j] >> 16) | (hb[2*j+1] & 0xFFFF0000u);
    m.u[j] = (mb[2*j] >> 16) | (mb[2*j+1] & 0xFFFF0000u);
    l.u[j] = (lb[2*j] >> 16) | (lb[2*j+1] & 0xFFFF0000u);
  }
  h4 = h.i4; m4 = m.i4; l4 = l.i4;
}

__device__ __forceinline__ bf16x8 asbf(const int4 x) { PKU u; u.i4 = x; return u.v; }

#define MFMA6(ACC, AH, AM, AL, BH, BM, BL)                                     \
  ACC = __builtin_amdgcn_mfma_f32_16x16x32_bf16(AH, BH, ACC, 0, 0, 0);         \
  ACC = __builtin_amdgcn_mfma_f32_16x16x32_bf16(AM, BH, ACC, 0, 0, 0);         \
  ACC = __builtin_amdgcn_mfma_f32_16x16x32_bf16(AH, BM, ACC, 0, 0, 0);         \
  ACC = __builtin_amdgcn_mfma_f32_16x16x32_bf16(AL, BH, ACC, 0, 0, 0);         \
  ACC = __builtin_amdgcn_mfma_f32_16x16x32_bf16(AH, BL, ACC, 0, 0, 0);         \
  ACC = __builtin_amdgcn_mfma_f32_16x16x32_bf16(AM, BM, ACC, 0, 0, 0);

// 512 threads (8 waves), 256 tokens/block, grid 512, 8 barriers per block.
// Every wave stages one (k-sub, nt) slice of the gate planes inline.
__global__ __launch_bounds__(512, 4)
void router_gemm_kernel(const float* __restrict__ hidden,
                        const float* __restrict__ gate,
                        float* __restrict__ pw,
                        float* __restrict__ accum) {
  __shared__ int4 bbuf[2][CHU];         // 48 KB double-buffered B planes

  const int tid   = threadIdx.x;
  const int lane  = tid & 63;
  const int wave  = tid >> 6;
  const int col16 = lane & 15;
  const int kq    = lane >> 4;
  const int part  = blockIdx.x & 7;     // fast dim -> pinned XCD for B slice
  const int tg    = blockIdx.x >> 3;
  const int tok0  = tg * 256 + wave * 32;

  if (blockIdx.x == 0 && tid < 128) accum[tid] = 0.f;  // plain stores

  const float* aP0 = hidden + (size_t)(tok0 + col16) * HDIM + part * KPW + kq * 8;
  const float* aP1 = aP0 + (size_t)16 * HDIM;
  // staging role: wave -> (k-sub, nt-quarter)
  const int snt = wave & 3;             // nt this wave stages
  const int ssb = wave >> 2;            // k-sub (0: k 0-31, 1: k 32-63)
  const float* gB = gate + (size_t)(snt * 16 + col16) * HDIM
                         + part * KPW + ssb * 32 + kq * 8;
  int4* const sdst = &bbuf[0][ssb * 768 + snt * 3 * 64 + lane];  // +CHU for buf1

  f32x4 acc0[4], acc1[4];
#pragma unroll
  for (int nt = 0; nt < 4; ++nt) {
    acc0[nt] = (f32x4){0.f, 0.f, 0.f, 0.f};
    acc1[nt] = (f32x4){0.f, 0.f, 0.f, 0.f};
  }

  // ---- prologue: split chunk 0 into buf0; prefetch gate chunk 1; A sub0 ----
  {
    int4 h, m, l;
    split8(L(gB), L(gB + 4), h, m, l);
    sdst[0] = h; sdst[64] = m; sdst[128] = l;
  }
  float4 g0 = L(gB + 64), g1 = L(gB + 68);
  float4 a00 = L(aP0), a01 = L(aP0 + 4);
  float4 a10 = L(aP1), a11 = L(aP1 + 4);
  __syncthreads();                       // buf0 + A(0,sub0) ready

#pragma unroll 1
  for (int c = 0; c < NCHK; ++c) {
    const int cur = c & 1;
    const int kb  = c * 64;
    // issue sub1 A loads (consumed after MFMA sub0)
    float4 b00 = L(aP0 + kb + 32), b01 = L(aP0 + kb + 36);
    float4 b10 = L(aP1 + kb + 32), b11 = L(aP1 + kb + 36);

    int4 h4, m4, l4;
    split8(a00, a01, h4, m4, l4);
    const bf16x8 a0h = asbf(h4), a0m = asbf(m4), a0l = asbf(l4);
    split8(a10, a11, h4, m4, l4);
    const bf16x8 a1h = asbf(h4), a1m = asbf(m4), a1l = asbf(l4);
#pragma unroll
    for (int nt = 0; nt < 4; ++nt) {
      const bf16x8 bh = asbf(bbuf[cur][(nt * 3 + 0) * 64 + lane]);
      const bf16x8 bm = asbf(bbuf[cur][(nt * 3 + 1) * 64 + lane]);
      const bf16x8 bl = asbf(bbuf[cur][(nt * 3 + 2) * 64 + lane]);
      MFMA6(acc0[nt], a0h, a0m, a0l, bh, bm, bl);
      MFMA6(acc1[nt], a1h, a1m, a1l, bh, bm, bl);
    }
    // issue next-chunk sub0 A loads (covered by MFMA sub1 + barrier)
    if (c + 1 < NCHK) {
      a00 = L(aP0 + kb + 64); a01 = L(aP0 + kb + 68);
      a10 = L(aP1 + kb + 64); a11 = L(aP1 + kb + 68);
    }
    // MFMA sub1
    split8(b00, b01, h4, m4, l4);
    const bf16x8 c0h = asbf(h4), c0m = asbf(m4), c0l = asbf(l4);
    split8(b10, b11, h4, m4, l4);
    const bf16x8 c1h = asbf(h4), c1m = asbf(m4), c1l = asbf(l4);
#pragma unroll
    for (int nt = 0; nt < 4; ++nt) {
      const bf16x8 bh = asbf(bbuf[cur][768 + (nt * 3 + 0) * 64 + lane]);
      const bf16x8 bm = asbf(bbuf[cur][768 + (nt * 3 + 1) * 64 + lane]);
      const bf16x8 bl = asbf(bbuf[cur][768 + (nt * 3 + 2) * 64 + lane]);
      MFMA6(acc0[nt], c0h, c0m, c0l, bh, bm, bl);
      MFMA6(acc1[nt], c1h, c1m, c1l, bh, bm, bl);
    }
    // write-late: split gate(c+1) from regs, then issue gate(c+2) loads
    if (c + 1 < NCHK) {
      int4 h, m, l;
      split8(g0, g1, h, m, l);
      int4* d = sdst + (cur ^ 1) * CHU;
      d[0] = h; d[64] = m; d[128] = l;
      if (c + 2 < NCHK) {
        g0 = L(gB + kb + 128); g1 = L(gB + kb + 132);
      }
    }
    __syncthreads();                     // buf[cur] consumed; c+1 planes landed
  }

  // partials[part][tok][e]
  float* prow = pw + (size_t)part * TOKENS * 64;
#pragma unroll
  for (int f = 0; f < 2; ++f)
#pragma unroll
    for (int nt = 0; nt < 4; ++nt)
#pragma unroll
      for (int r = 0; r < 4; ++r) {
        const int tok = tok0 + f * 16 + kq * 4 + r;
        prow[(size_t)tok * 64 + nt * 16 + col16] = f ? acc1[nt][r] : acc0[nt][r];
      }
}

__global__ __launch_bounds__(256, 4)
void router_top2_kernel(const float* __restrict__ pw,
                        float* __restrict__ out,
                        float* __restrict__ accum) {
  __shared__ float red[2][4][4][16];     // [psum/cnt][wave][slice][16]

  const int tid  = threadIdx.x;
  const int lane = tid & 63, wave = tid >> 6;
  const int tok  = blockIdx.x * 64 + wave * 16 + (lane >> 2);
  const int sl   = lane & 3;             // expert slice: e in [sl*16, sl*16+16)

  f32x4 s[4];
#pragma unroll
  for (int q = 0; q < 4; ++q) s[q] = (f32x4){0.f, 0.f, 0.f, 0.f};
#pragma unroll
  for (int p = 0; p < NPARTS; ++p) {
    const float* b = pw + ((size_t)p * TOKENS + tok) * 64 + sl * 16;
#pragma unroll
    for (int q = 0; q < 4; ++q) {
      const float4 v = L(b + q * 4);
      s[q][0] += v.x; s[q][1] += v.y; s[q][2] += v.z; s[q][3] += v.w;
    }
  }

  // in-lane top-2 over 16 experts, ascending index (tie -> lower)
  float v1 = s[0][0]; int i1 = sl * 16;
  float v2 = -3.4e38f; int i2 = 1 << 30;
#pragma unroll
  for (int q = 0; q < 4; ++q)
#pragma unroll
    for (int j = 0; j < 4; ++j) {
      if (q == 0 && j == 0) continue;
      const float v = s[q][j]; const int ix = sl * 16 + q * 4 + j;
      if (v > v1)      { v2 = v1; i2 = i1; v1 = v; i1 = ix; }
      else if (v > v2) { v2 = v;  i2 = ix; }
    }
  // merge across the 4 slice-lanes of this token
#pragma unroll
  for (int m = 1; m < 4; m <<= 1) {
    const float ov1 = __shfl_xor(v1, m, 64); const int oi1 = __shfl_xor(i1, m, 64);
    const float ov2 = __shfl_xor(v2, m, 64); const int oi2 = __shfl_xor(i2, m, 64);
    const bool  ob  = (ov1 > v1) || (ov1 == v1 && oi1 < i1);
    const float lv  = ob ? v1  : ov1;  const int li = ob ? i1  : oi1;
    const float rv  = ob ? ov2 : v2;   const int ri = ob ? oi2 : i2;
    v1 = ob ? ov1 : v1; i1 = ob ? oi1 : i1;
    const bool  ab  = (lv > rv) || (lv == rv && li < ri);
    v2 = ab ? lv : rv;  i2 = ab ? li : ri;
  }
  // full softmax over 64 experts (v1 = true max in all 4 lanes)
  float el[16]; float ls = 0.f;
#pragma unroll
  for (int q = 0; q < 4; ++q)
#pragma unroll
    for (int j = 0; j < 4; ++j) { el[q*4+j] = expf(s[q][j] - v1); ls += el[q*4+j]; }
#pragma unroll
  for (int m = 1; m < 4; m <<= 1) ls += __shfl_xor(ls, m, 64);
  const float inv = 1.f / ls;

  float psum[16], cnt[16];
#pragma unroll
  for (int j = 0; j < 16; ++j) {
    psum[j] = el[j] * inv;
    const int ix = sl * 16 + j;
    cnt[j] = (float)((i1 == ix) + (i2 == ix));
  }

  if (sl == 0) {
    const float e2 = expf(v2 - v1);
    const float w1 = 1.f / (1.f + e2);
    out[tok * 2 + 0] = w1;
    out[tok * 2 + 1] = e2 * w1;
    out[(size_t)TOKENS * 2 + tok * 2 + 0] = (float)i1;
    out[(size_t)TOKENS * 2 + tok * 2 + 1] = (float)i2;
  }

  // per-expert stats: reduce over the 16 tokens of this wave (stride-4 lanes)
#pragma unroll
  for (int m = 4; m < 64; m <<= 1)
#pragma unroll
    for (int j = 0; j < 16; ++j) {
      psum[j] += __shfl_xor(psum[j], m, 64);
      cnt[j]  += __shfl_xor(cnt[j], m, 64);
    }
  if (lane < 4) {
#pragma unroll
    for (int j = 0; j < 16; ++j) {
      red[0][wave][sl][j] = psum[j];
      red[1][wave][sl][j] = cnt[j];
    }
  }
  __syncthreads();
  if (tid < 64) {
    const int sl2 = tid >> 4, j2 = tid & 15;
    float ps = 0.f, cs = 0.f;
#pragma unroll
    for (int w = 0; w < 4; ++w) { ps += red[0][w][sl2][j2]; cs += red[1][w][sl2][j2]; }
    atomicAdd(&accum[sl2 * 16 + j2], ps);
    atomicAdd(&accum[64 + sl2 * 16 + j2], cs);
  }
}

__global__ void router_loss_kernel(const float* __restrict__ accum,
                                   float* __restrict__ out) {
  const int l = threadIdx.x;  // 64 threads
  float term = accum[l] * accum[64 + l];   // P_sum_e * count_e
#pragma unroll
  for (int m = 1; m < 64; m <<= 1) term += __shfl_xor(term, m, 64);
  if (l == 0) {
    const float invN = 1.f / (float)TOKENS;
    out[(size_t)TOKENS * 4] = 0.01f * 64.f * term * invN * invN;
  }
}

extern "C" void kernel_launch(void* const* d_in, const int* in_sizes, int n_in,
                              void* d_out, int out_size, void* d_ws, size_t ws_size,
                              hipStream_t stream) {
  const float* hidden = (const float*)d_in[0];  // [4,4096,4096] f32
  const float* gate   = (const float*)d_in[1];  // [64,4096] f32
  float* out   = (float*)d_out;                 // 32768 w + 32768 idx + 1 loss

  float* accum = (float*)d_ws;                                   // 128 f32
  float* pw    = (float*)((char*)d_ws + 1024);                   // 33.5 MB partials

  router_gemm_kernel<<<(TOKENS / 256) * NPARTS, 512, 0, stream>>>(hidden, gate, pw, accum);
  router_top2_kernel<<<TOKENS / 64, 256, 0, stream>>>(pw, out, accum);
  router_loss_kernel<<<1, 64, 0, stream>>>(accum, out);
}

// Round 12
// 85.573 us; speedup vs baseline: 1.0321x; 1.0321x over previous
//
#include <hip/hip_runtime.h>

#define TOKENS 16384
#define HDIM   4096
#define NPARTS 4
#define KPW    (HDIM / NPARTS)      // 1024 k per K-part
#define NCHK   (KPW / 32)           // 32 chunks of 32 k per part
#define CHU    768                  // int4 units per chunk (4nt x 3 planes x 64)

typedef __attribute__((ext_vector_type(8))) short bf16x8;
typedef __attribute__((ext_vector_type(4))) float f32x4;

union PKU { unsigned int u[4]; int4 i4; bf16x8 v; };

__device__ __forceinline__ float4 L(const float* p) {
  return *reinterpret_cast<const float4*>(p);
}

// Exact 3-way bf16 split of 8 fp32: x = h + m + l (+O(2^-27) truncation)
__device__ __forceinline__ void split8(const float4 a, const float4 b,
                                       int4& h4, int4& m4, int4& l4) {
  const float e[8] = {a.x, a.y, a.z, a.w, b.x, b.y, b.z, b.w};
  unsigned int hb[8], mb[8], lb[8];
#pragma unroll
  for (int i = 0; i < 8; ++i) {
    const unsigned int xb = __float_as_uint(e[i]);
    hb[i] = xb & 0xFFFF0000u;
    const float r = e[i] - __uint_as_float(hb[i]);
    const unsigned int rb = __float_as_uint(r);
    mb[i] = rb & 0xFFFF0000u;
    const float r2 = r - __uint_as_float(mb[i]);
    lb[i] = __float_as_uint(r2);
  }
  PKU h, m, l;
#pragma unroll
  for (int j = 0; j < 4; ++j) {
    h.u[j] = (hb[2*j] >> 16) | (hb[2*j+1] & 0xFFFF0000u);
    m.u[j] = (mb[2*j] >> 16) | (mb[2*j+1] & 0xFFFF0000u);
    l.u[j] = (lb[2*j] >> 16) | (lb[2*j+1] & 0xFFFF0000u);
  }
  h4 = h.i4; m4 = m.i4; l4 = l.i4;
}

__device__ __forceinline__ bf16x8 asbf(const int4 x) { PKU u; u.i4 = x; return u.v; }

#define MFMA6(ACC, AH, AM, AL, BH, BM, BL)                                     \
  ACC = __builtin_amdgcn_mfma_f32_16x16x32_bf16(AH, BH, ACC, 0, 0, 0);         \
  ACC = __builtin_amdgcn_mfma_f32_16x16x32_bf16(AM, BH, ACC, 0, 0, 0);         \
  ACC = __builtin_amdgcn_mfma_f32_16x16x32_bf16(AH, BM, ACC, 0, 0, 0);         \
  ACC = __builtin_amdgcn_mfma_f32_16x16x32_bf16(AL, BH, ACC, 0, 0, 0);         \
  ACC = __builtin_amdgcn_mfma_f32_16x16x32_bf16(AH, BL, ACC, 0, 0, 0);         \
  ACC = __builtin_amdgcn_mfma_f32_16x16x32_bf16(AM, BM, ACC, 0, 0, 0);

// 512 threads (8 waves), 128 tokens/block (16/wave), grid 512 (2 blocks/CU).
// Waves 0-3 split the gate slice into bf16 h/m/l planes inline
// (load c+2 early, write c+1 late).
__global__ __launch_bounds__(512, 4)
void router_gemm_kernel(const float* __restrict__ hidden,
                        const float* __restrict__ gate,
                        float* __restrict__ pw,
                        float* __restrict__ accum) {
  __shared__ int4 bbuf[2][CHU];         // 24 KB double-buffered B planes

  const int tid   = threadIdx.x;
  const int lane  = tid & 63;
  const int wave  = tid >> 6;
  const int col16 = lane & 15;
  const int kq    = lane >> 4;
  const int part  = blockIdx.x & 3;     // fast dim -> B slice L2 locality
  const int tg    = blockIdx.x >> 2;
  const int tok0  = tg * 128 + wave * 16;

  if (blockIdx.x == 0 && tid < 128) accum[tid] = 0.f;  // plain stores

  const float* aP0 = hidden + (size_t)(tok0 + col16) * HDIM + part * KPW + kq * 8;
  // staging source (valid for waves 0-3): gate row snt*16+col16, k = kq*8..
  const int snt = wave & 3;
  const float* gB = gate + (size_t)(snt * 16 + col16) * HDIM + part * KPW + kq * 8;
  const bool stager = (tid < 256);

  f32x4 acc0[4];
#pragma unroll
  for (int nt = 0; nt < 4; ++nt) acc0[nt] = (f32x4){0.f, 0.f, 0.f, 0.f};

  // ---- prologue: split chunk 0 into buf0; prefetch gate chunk 1; A(0) ----
  if (stager) {
    int4 h, m, l;
    split8(L(gB), L(gB + 4), h, m, l);
    int4* d = &bbuf[0][snt * 3 * 64 + lane];
    d[0] = h; d[64] = m; d[128] = l;
  }
  float4 g0, g1;
  if (stager) { g0 = L(gB + 32); g1 = L(gB + 36); }
  float4 a00 = L(aP0), a01 = L(aP0 + 4);
  __syncthreads();                       // buf0 + A(0) ready

#pragma unroll 1
  for (int c = 0; c < NCHK; ++c) {
    const int cur = c & 1;
    float4 n00, n01;
    if (c + 1 < NCHK) {                  // A prefetch (issue early)
      const int ko = (c + 1) * 32;
      n00 = L(aP0 + ko); n01 = L(aP0 + ko + 4);
    }
    int4 h4, m4, l4;
    split8(a00, a01, h4, m4, l4);
    const bf16x8 a0h = asbf(h4), a0m = asbf(m4), a0l = asbf(l4);
#pragma unroll
    for (int nt = 0; nt < 4; ++nt) {
      const bf16x8 bh = asbf(bbuf[cur][(nt * 3 + 0) * 64 + lane]);
      const bf16x8 bm = asbf(bbuf[cur][(nt * 3 + 1) * 64 + lane]);
      const bf16x8 bl = asbf(bbuf[cur][(nt * 3 + 2) * 64 + lane]);
      MFMA6(acc0[nt], a0h, a0m, a0l, bh, bm, bl);
    }
    // write-late: split gate(c+1) (loaded a chunk ago) into the other buffer,
    // then immediately issue gate(c+2) loads so they land during next chunk.
    if (c + 1 < NCHK && stager) {
      int4 h, m, l;
      split8(g0, g1, h, m, l);
      int4* d = &bbuf[cur ^ 1][snt * 3 * 64 + lane];
      d[0] = h; d[64] = m; d[128] = l;
      if (c + 2 < NCHK) {
        const int go = (c + 2) * 32;
        g0 = L(gB + go); g1 = L(gB + go + 4);
      }
    }
    __syncthreads();                     // buf[cur] consumed; c+1 planes landed
    a00 = n00; a01 = n01;
  }

  // partials[part][tok][e]
  float* prow = pw + (size_t)part * TOKENS * 64;
#pragma unroll
  for (int nt = 0; nt < 4; ++nt)
#pragma unroll
    for (int r = 0; r < 4; ++r) {
      const int tok = tok0 + kq * 4 + r;
      prow[(size_t)tok * 64 + nt * 16 + col16] = acc0[nt][r];
    }
}

__global__ __launch_bounds__(256, 4)
void router_top2_kernel(const float* __restrict__ pw,
                        float* __restrict__ out,
                        float* __restrict__ accum) {
  __shared__ float red[2][4][4][16];     // [psum/cnt][wave][slice][16]

  const int tid  = threadIdx.x;
  const int lane = tid & 63, wave = tid >> 6;
  const int tok  = blockIdx.x * 64 + wave * 16 + (lane >> 2);
  const int sl   = lane & 3;             // expert slice: e in [sl*16, sl*16+16)

  f32x4 s[4];
#pragma unroll
  for (int q = 0; q < 4; ++q) s[q] = (f32x4){0.f, 0.f, 0.f, 0.f};
#pragma unroll
  for (int p = 0; p < NPARTS; ++p) {
    const float* b = pw + ((size_t)p * TOKENS + tok) * 64 + sl * 16;
#pragma unroll
    for (int q = 0; q < 4; ++q) {
      const float4 v = L(b + q * 4);
      s[q][0] += v.x; s[q][1] += v.y; s[q][2] += v.z; s[q][3] += v.w;
    }
  }

  // in-lane top-2 over 16 experts, ascending index (tie -> lower)
  float v1 = s[0][0]; int i1 = sl * 16;
  float v2 = -3.4e38f; int i2 = 1 << 30;
#pragma unroll
  for (int q = 0; q < 4; ++q)
#pragma unroll
    for (int j = 0; j < 4; ++j) {
      if (q == 0 && j == 0) continue;
      const float v = s[q][j]; const int ix = sl * 16 + q * 4 + j;
      if (v > v1)      { v2 = v1; i2 = i1; v1 = v; i1 = ix; }
      else if (v > v2) { v2 = v;  i2 = ix; }
    }
  // merge across the 4 slice-lanes of this token
#pragma unroll
  for (int m = 1; m < 4; m <<= 1) {
    const float ov1 = __shfl_xor(v1, m, 64); const int oi1 = __shfl_xor(i1, m, 64);
    const float ov2 = __shfl_xor(v2, m, 64); const int oi2 = __shfl_xor(i2, m, 64);
    const bool  ob  = (ov1 > v1) || (ov1 == v1 && oi1 < i1);
    const float lv  = ob ? v1  : ov1;  const int li = ob ? i1  : oi1;
    const float rv  = ob ? ov2 : v2;   const int ri = ob ? oi2 : i2;
    v1 = ob ? ov1 : v1; i1 = ob ? oi1 : i1;
    const bool  ab  = (lv > rv) || (lv == rv && li < ri);
    v2 = ab ? lv : rv;  i2 = ab ? li : ri;
  }
  // full softmax over 64 experts (v1 = true max in all 4 lanes)
  float el[16]; float ls = 0.f;
#pragma unroll
  for (int q = 0; q < 4; ++q)
#pragma unroll
    for (int j = 0; j < 4; ++j) { el[q*4+j] = expf(s[q][j] - v1); ls += el[q*4+j]; }
#pragma unroll
  for (int m = 1; m < 4; m <<= 1) ls += __shfl_xor(ls, m, 64);
  const float inv = 1.f / ls;

  float psum[16], cnt[16];
#pragma unroll
  for (int j = 0; j < 16; ++j) {
    psum[j] = el[j] * inv;
    const int ix = sl * 16 + j;
    cnt[j] = (float)((i1 == ix) + (i2 == ix));
  }

  if (sl == 0) {
    const float e2 = expf(v2 - v1);
    const float w1 = 1.f / (1.f + e2);
    out[tok * 2 + 0] = w1;
    out[tok * 2 + 1] = e2 * w1;
    out[(size_t)TOKENS * 2 + tok * 2 + 0] = (float)i1;
    out[(size_t)TOKENS * 2 + tok * 2 + 1] = (float)i2;
  }

  // per-expert stats: reduce over the 16 tokens of this wave (stride-4 lanes)
#pragma unroll
  for (int m = 4; m < 64; m <<= 1)
#pragma unroll
    for (int j = 0; j < 16; ++j) {
      psum[j] += __shfl_xor(psum[j], m, 64);
      cnt[j]  += __shfl_xor(cnt[j], m, 64);
    }
  if (lane < 4) {
#pragma unroll
    for (int j = 0; j < 16; ++j) {
      red[0][wave][sl][j] = psum[j];
      red[1][wave][sl][j] = cnt[j];
    }
  }
  __syncthreads();
  if (tid < 64) {
    const int sl2 = tid >> 4, j2 = tid & 15;
    float ps = 0.f, cs = 0.f;
#pragma unroll
    for (int w = 0; w < 4; ++w) { ps += red[0][w][sl2][j2]; cs += red[1][w][sl2][j2]; }
    atomicAdd(&accum[sl2 * 16 + j2], ps);
    atomicAdd(&accum[64 + sl2 * 16 + j2], cs);
  }
}

__global__ void router_loss_kernel(const float* __restrict__ accum,
                                   float* __restrict__ out) {
  const int l = threadIdx.x;  // 64 threads
  float term = accum[l] * accum[64 + l];   // P_sum_e * count_e
#pragma unroll
  for (int m = 1; m < 64; m <<= 1) term += __shfl_xor(term, m, 64);
  if (l == 0) {
    const float invN = 1.f / (float)TOKENS;
    out[(size_t)TOKENS * 4] = 0.01f * 64.f * term * invN * invN;
  }
}

extern "C" void kernel_launch(void* const* d_in, const int* in_sizes, int n_in,
                              void* d_out, int out_size, void* d_ws, size_t ws_size,
                              hipStream_t stream) {
  const float* hidden = (const float*)d_in[0];  // [4,4096,4096] f32
  const float* gate   = (const float*)d_in[1];  // [64,4096] f32
  float* out   = (float*)d_out;                 // 32768 w + 32768 idx + 1 loss

  float* accum = (float*)d_ws;                                   // 128 f32
  float* pw    = (float*)((char*)d_ws + 1024);                   // 16.8 MB partials

  router_gemm_kernel<<<(TOKENS / 128) * NPARTS, 512, 0, stream>>>(hidden, gate, pw, accum);
  router_top2_kernel<<<TOKENS / 64, 256, 0, stream>>>(pw, out, accum);
  router_loss_kernel<<<1, 64, 0, stream>>>(accum, out);
}

// Round 13
// 85.215 us; speedup vs baseline: 1.0364x; 1.0042x over previous
//
#include <hip/hip_runtime.h>

#define TOKENS 16384
#define HDIM   4096
#define NPARTS 4
#define KPW    (HDIM / NPARTS)      // 1024 k per K-part
#define NCHK   (KPW / 32)           // 32 chunks of 32 k per part
#define CHU    768                  // int4 units per chunk (4nt x 3 planes x 64)

typedef __attribute__((ext_vector_type(8))) short bf16x8;
typedef __attribute__((ext_vector_type(4))) float f32x4;

union PKU { unsigned int u[4]; int4 i4; bf16x8 v; };

__device__ __forceinline__ float4 L(const float* p) {
  return *reinterpret_cast<const float4*>(p);
}

// Exact 3-way bf16 split of 8 fp32: x = h + m + l (+O(2^-27) truncation)
__device__ __forceinline__ void split8(const float4 a, const float4 b,
                                       int4& h4, int4& m4, int4& l4) {
  const float e[8] = {a.x, a.y, a.z, a.w, b.x, b.y, b.z, b.w};
  unsigned int hb[8], mb[8], lb[8];
#pragma unroll
  for (int i = 0; i < 8; ++i) {
    const unsigned int xb = __float_as_uint(e[i]);
    hb[i] = xb & 0xFFFF0000u;
    const float r = e[i] - __uint_as_float(hb[i]);
    const unsigned int rb = __float_as_uint(r);
    mb[i] = rb & 0xFFFF0000u;
    const float r2 = r - __uint_as_float(mb[i]);
    lb[i] = __float_as_uint(r2);
  }
  PKU h, m, l;
#pragma unroll
  for (int j = 0; j < 4; ++j) {
    h.u[j] = (hb[2*j] >> 16) | (hb[2*j+1] & 0xFFFF0000u);
    m.u[j] = (mb[2*j] >> 16) | (mb[2*j+1] & 0xFFFF0000u);
    l.u[j] = (lb[2*j] >> 16) | (lb[2*j+1] & 0xFFFF0000u);
  }
  h4 = h.i4; m4 = m.i4; l4 = l.i4;
}

__device__ __forceinline__ bf16x8 asbf(const int4 x) { PKU u; u.i4 = x; return u.v; }

#define MFMA6(ACC, AH, AM, AL, BH, BM, BL)                                     \
  ACC = __builtin_amdgcn_mfma_f32_16x16x32_bf16(AH, BH, ACC, 0, 0, 0);         \
  ACC = __builtin_amdgcn_mfma_f32_16x16x32_bf16(AM, BH, ACC, 0, 0, 0);         \
  ACC = __builtin_amdgcn_mfma_f32_16x16x32_bf16(AH, BM, ACC, 0, 0, 0);         \
  ACC = __builtin_amdgcn_mfma_f32_16x16x32_bf16(AL, BH, ACC, 0, 0, 0);         \
  ACC = __builtin_amdgcn_mfma_f32_16x16x32_bf16(AH, BL, ACC, 0, 0, 0);         \
  ACC = __builtin_amdgcn_mfma_f32_16x16x32_bf16(AM, BM, ACC, 0, 0, 0);

// 512 threads (8 waves), 128 tokens/block (16/wave), grid 512 (2 blocks/CU).
// part = blockIdx>>7 (slow) => all 4 parts of a token group share one XCD.
__global__ __launch_bounds__(512, 4)
void router_gemm_kernel(const float* __restrict__ hidden,
                        const float* __restrict__ gate,
                        float* __restrict__ pw) {
  __shared__ int4 bbuf[2][CHU];         // 24 KB double-buffered B planes

  const int tid   = threadIdx.x;
  const int lane  = tid & 63;
  const int wave  = tid >> 6;
  const int col16 = lane & 15;
  const int kq    = lane >> 4;
  const int part  = blockIdx.x >> 7;    // slow dim: 0..3
  const int tg    = blockIdx.x & 127;   // XCD = tg % 8 for all parts of tg
  const int tok0  = tg * 128 + wave * 16;

  const float* aP0 = hidden + (size_t)(tok0 + col16) * HDIM + part * KPW + kq * 8;
  // staging source (valid for waves 0-3): gate row snt*16+col16, k = kq*8..
  const int snt = wave & 3;
  const float* gB = gate + (size_t)(snt * 16 + col16) * HDIM + part * KPW + kq * 8;
  const bool stager = (tid < 256);

  f32x4 acc0[4];
#pragma unroll
  for (int nt = 0; nt < 4; ++nt) acc0[nt] = (f32x4){0.f, 0.f, 0.f, 0.f};

  // ---- prologue: split chunk 0 into buf0; prefetch gate chunk 1; A(0) ----
  if (stager) {
    int4 h, m, l;
    split8(L(gB), L(gB + 4), h, m, l);
    int4* d = &bbuf[0][snt * 3 * 64 + lane];
    d[0] = h; d[64] = m; d[128] = l;
  }
  float4 g0, g1;
  if (stager) { g0 = L(gB + 32); g1 = L(gB + 36); }
  float4 a00 = L(aP0), a01 = L(aP0 + 4);
  __syncthreads();                       // buf0 + A(0) ready

#pragma unroll 1
  for (int c = 0; c < NCHK; ++c) {
    const int cur = c & 1;
    float4 n00, n01;
    if (c + 1 < NCHK) {                  // A prefetch (issue early)
      const int ko = (c + 1) * 32;
      n00 = L(aP0 + ko); n01 = L(aP0 + ko + 4);
    }
    int4 h4, m4, l4;
    split8(a00, a01, h4, m4, l4);
    const bf16x8 a0h = asbf(h4), a0m = asbf(m4), a0l = asbf(l4);
#pragma unroll
    for (int nt = 0; nt < 4; ++nt) {
      const bf16x8 bh = asbf(bbuf[cur][(nt * 3 + 0) * 64 + lane]);
      const bf16x8 bm = asbf(bbuf[cur][(nt * 3 + 1) * 64 + lane]);
      const bf16x8 bl = asbf(bbuf[cur][(nt * 3 + 2) * 64 + lane]);
      MFMA6(acc0[nt], a0h, a0m, a0l, bh, bm, bl);
    }
    // write-late: split gate(c+1) (loaded a chunk ago) into the other buffer,
    // then immediately issue gate(c+2) loads so they land during next chunk.
    if (c + 1 < NCHK && stager) {
      int4 h, m, l;
      split8(g0, g1, h, m, l);
      int4* d = &bbuf[cur ^ 1][snt * 3 * 64 + lane];
      d[0] = h; d[64] = m; d[128] = l;
      if (c + 2 < NCHK) {
        const int go = (c + 2) * 32;
        g0 = L(gB + go); g1 = L(gB + go + 4);
      }
    }
    __syncthreads();                     // buf[cur] consumed; c+1 planes landed
    a00 = n00; a01 = n01;
  }

  // partials[part][tok][e] — stays in this token group's XCD L2
  float* prow = pw + (size_t)part * TOKENS * 64;
#pragma unroll
  for (int nt = 0; nt < 4; ++nt)
#pragma unroll
    for (int r = 0; r < 4; ++r) {
      const int tok = tok0 + kq * 4 + r;
      prow[(size_t)tok * 64 + nt * 16 + col16] = acc0[nt][r];
    }
}

// Block b serves tokens whose pw lives on XCD b&7 (same-XCD L2 reads).
// Per-expert stats -> plain per-block stores in pb[b][128] (no atomics).
__global__ __launch_bounds__(256, 4)
void router_top2_kernel(const float* __restrict__ pw,
                        float* __restrict__ out,
                        float* __restrict__ pb) {
  __shared__ float red[2][4][4][16];     // [psum/cnt][wave][slice][16]

  const int tid  = threadIdx.x;
  const int lane = tid & 63, wave = tid >> 6;
  const int b    = blockIdx.x;
  const int xcd  = b & 7, j = b >> 3;
  const int tok0 = (xcd + 8 * (j >> 1)) * 128 + (j & 1) * 64;
  const int tok  = tok0 + wave * 16 + (lane >> 2);
  const int sl   = lane & 3;             // expert slice: e in [sl*16, sl*16+16)

  f32x4 s[4];
#pragma unroll
  for (int q = 0; q < 4; ++q) s[q] = (f32x4){0.f, 0.f, 0.f, 0.f};
#pragma unroll
  for (int p = 0; p < NPARTS; ++p) {
    const float* bp = pw + ((size_t)p * TOKENS + tok) * 64 + sl * 16;
#pragma unroll
    for (int q = 0; q < 4; ++q) {
      const float4 v = L(bp + q * 4);
      s[q][0] += v.x; s[q][1] += v.y; s[q][2] += v.z; s[q][3] += v.w;
    }
  }

  // in-lane top-2 over 16 experts, ascending index (tie -> lower)
  float v1 = s[0][0]; int i1 = sl * 16;
  float v2 = -3.4e38f; int i2 = 1 << 30;
#pragma unroll
  for (int q = 0; q < 4; ++q)
#pragma unroll
    for (int jj = 0; jj < 4; ++jj) {
      if (q == 0 && jj == 0) continue;
      const float v = s[q][jj]; const int ix = sl * 16 + q * 4 + jj;
      if (v > v1)      { v2 = v1; i2 = i1; v1 = v; i1 = ix; }
      else if (v > v2) { v2 = v;  i2 = ix; }
    }
  // merge across the 4 slice-lanes of this token
#pragma unroll
  for (int m = 1; m < 4; m <<= 1) {
    const float ov1 = __shfl_xor(v1, m, 64); const int oi1 = __shfl_xor(i1, m, 64);
    const float ov2 = __shfl_xor(v2, m, 64); const int oi2 = __shfl_xor(i2, m, 64);
    const bool  ob  = (ov1 > v1) || (ov1 == v1 && oi1 < i1);
    const float lv  = ob ? v1  : ov1;  const int li = ob ? i1  : oi1;
    const float rv  = ob ? ov2 : v2;   const int ri = ob ? oi2 : i2;
    v1 = ob ? ov1 : v1; i1 = ob ? oi1 : i1;
    const bool  ab  = (lv > rv) || (lv == rv && li < ri);
    v2 = ab ? lv : rv;  i2 = ab ? li : ri;
  }
  // full softmax over 64 experts (v1 = true max in all 4 lanes)
  float el[16]; float ls = 0.f;
#pragma unroll
  for (int q = 0; q < 4; ++q)
#pragma unroll
    for (int jj = 0; jj < 4; ++jj) { el[q*4+jj] = expf(s[q][jj] - v1); ls += el[q*4+jj]; }
#pragma unroll
  for (int m = 1; m < 4; m <<= 1) ls += __shfl_xor(ls, m, 64);
  const float inv = 1.f / ls;

  float psum[16], cnt[16];
#pragma unroll
  for (int jj = 0; jj < 16; ++jj) {
    psum[jj] = el[jj] * inv;
    const int ix = sl * 16 + jj;
    cnt[jj] = (float)((i1 == ix) + (i2 == ix));
  }

  if (sl == 0) {
    const float e2 = expf(v2 - v1);
    const float w1 = 1.f / (1.f + e2);
    out[tok * 2 + 0] = w1;
    out[tok * 2 + 1] = e2 * w1;
    out[(size_t)TOKENS * 2 + tok * 2 + 0] = (float)i1;
    out[(size_t)TOKENS * 2 + tok * 2 + 1] = (float)i2;
  }

  // per-expert stats: reduce over the 16 tokens of this wave (stride-4 lanes)
#pragma unroll
  for (int m = 4; m < 64; m <<= 1)
#pragma unroll
    for (int jj = 0; jj < 16; ++jj) {
      psum[jj] += __shfl_xor(psum[jj], m, 64);
      cnt[jj]  += __shfl_xor(cnt[jj], m, 64);
    }
  if (lane < 4) {
#pragma unroll
    for (int jj = 0; jj < 16; ++jj) {
      red[0][wave][sl][jj] = psum[jj];
      red[1][wave][sl][jj] = cnt[jj];
    }
  }
  __syncthreads();
  if (tid < 64) {
    const int sl2 = tid >> 4, j2 = tid & 15;
    float ps = 0.f, cs = 0.f;
#pragma unroll
    for (int w = 0; w < 4; ++w) { ps += red[0][w][sl2][j2]; cs += red[1][w][sl2][j2]; }
    pb[(size_t)b * 128 + sl2 * 16 + j2]      = ps;   // plain stores
    pb[(size_t)b * 128 + 64 + sl2 * 16 + j2] = cs;
  }
}

__global__ void router_loss_kernel(const float* __restrict__ pb,
                                   float* __restrict__ out) {
  __shared__ float red[2][4][64];
  const int tid = threadIdx.x;          // 256
  const int e = tid & 63, q = tid >> 6; // q = block-quarter
  float ps = 0.f, cs = 0.f;
#pragma unroll 4
  for (int b = q * 64; b < q * 64 + 64; ++b) {
    ps += pb[(size_t)b * 128 + e];
    cs += pb[(size_t)b * 128 + 64 + e];
  }
  red[0][q][e] = ps; red[1][q][e] = cs;
  __syncthreads();
  if (tid < 64) {
    const float P = red[0][0][tid] + red[0][1][tid] + red[0][2][tid] + red[0][3][tid];
    const float C = red[1][0][tid] + red[1][1][tid] + red[1][2][tid] + red[1][3][tid];
    float term = P * C;
#pragma unroll
    for (int m = 1; m < 64; m <<= 1) term += __shfl_xor(term, m, 64);
    if (tid == 0) {
      const float invN = 1.f / (float)TOKENS;
      out[(size_t)TOKENS * 4] = 0.01f * 64.f * term * invN * invN;
    }
  }
}

extern "C" void kernel_launch(void* const* d_in, const int* in_sizes, int n_in,
                              void* d_out, int out_size, void* d_ws, size_t ws_size,
                              hipStream_t stream) {
  const float* hidden = (const float*)d_in[0];  // [4,4096,4096] f32
  const float* gate   = (const float*)d_in[1];  // [64,4096] f32
  float* out   = (float*)d_out;                 // 32768 w + 32768 idx + 1 loss

  float* pb = (float*)d_ws;                                // 128 KB block partials
  float* pw = (float*)((char*)d_ws + 131072);              // 16.8 MB partials

  router_gemm_kernel<<<NPARTS * (TOKENS / 128), 512, 0, stream>>>(hidden, gate, pw);
  router_top2_kernel<<<TOKENS / 64, 256, 0, stream>>>(pw, out, pb);
  router_loss_kernel<<<1, 256, 0, stream>>>(pb, out);
}

// Round 14
// 80.989 us; speedup vs baseline: 1.0905x; 1.0522x over previous
//
#include <hip/hip_runtime.h>

#define TOKENS 16384
#define HDIM   4096
#define NPARTS 4
#define KPW    (HDIM / NPARTS)      // 1024 k per K-part
#define NCHK   (KPW / 64)           // 16 chunks of 64 k per part
#define CHU    1536                 // int4 units per chunk (2ksub x 4nt x 3pl x 64)

typedef __attribute__((ext_vector_type(8))) short bf16x8;
typedef __attribute__((ext_vector_type(4))) float f32x4;

union PKU { unsigned int u[4]; int4 i4; bf16x8 v; };

__device__ __forceinline__ float4 L(const float* p) {
  return *reinterpret_cast<const float4*>(p);
}

// Exact 3-way bf16 split of 8 fp32: x = h + m + l (+O(2^-27) truncation)
__device__ __forceinline__ void split8(const float4 a, const float4 b,
                                       int4& h4, int4& m4, int4& l4) {
  const float e[8] = {a.x, a.y, a.z, a.w, b.x, b.y, b.z, b.w};
  unsigned int hb[8], mb[8], lb[8];
#pragma unroll
  for (int i = 0; i < 8; ++i) {
    const unsigned int xb = __float_as_uint(e[i]);
    hb[i] = xb & 0xFFFF0000u;
    const float r = e[i] - __uint_as_float(hb[i]);
    const unsigned int rb = __float_as_uint(r);
    mb[i] = rb & 0xFFFF0000u;
    const float r2 = r - __uint_as_float(mb[i]);
    lb[i] = __float_as_uint(r2);
  }
  PKU h, m, l;
#pragma unroll
  for (int j = 0; j < 4; ++j) {
    h.u[j] = (hb[2*j] >> 16) | (hb[2*j+1] & 0xFFFF0000u);
    m.u[j] = (mb[2*j] >> 16) | (mb[2*j+1] & 0xFFFF0000u);
    l.u[j] = (lb[2*j] >> 16) | (lb[2*j+1] & 0xFFFF0000u);
  }
  h4 = h.i4; m4 = m.i4; l4 = l.i4;
}

__device__ __forceinline__ bf16x8 asbf(const int4 x) { PKU u; u.i4 = x; return u.v; }

#define MFMA6(ACC, AH, AM, AL, BH, BM, BL)                                     \
  ACC = __builtin_amdgcn_mfma_f32_16x16x32_bf16(AH, BH, ACC, 0, 0, 0);         \
  ACC = __builtin_amdgcn_mfma_f32_16x16x32_bf16(AM, BH, ACC, 0, 0, 0);         \
  ACC = __builtin_amdgcn_mfma_f32_16x16x32_bf16(AH, BM, ACC, 0, 0, 0);         \
  ACC = __builtin_amdgcn_mfma_f32_16x16x32_bf16(AL, BH, ACC, 0, 0, 0);         \
  ACC = __builtin_amdgcn_mfma_f32_16x16x32_bf16(AH, BL, ACC, 0, 0, 0);         \
  ACC = __builtin_amdgcn_mfma_f32_16x16x32_bf16(AM, BM, ACC, 0, 0, 0);

// 512 threads (8 waves), 128 tokens/block (16/wave), grid 512 (2 blocks/CU),
// BK=64 -> 16 barriers. Every wave stages one (ksub, nt) gate slice inline.
__global__ __launch_bounds__(512, 4)
void router_gemm_kernel(const float* __restrict__ hidden,
                        const float* __restrict__ gate,
                        float* __restrict__ pw) {
  __shared__ int4 bbuf[2][CHU];         // 48 KB double-buffered B planes

  const int tid   = threadIdx.x;
  const int lane  = tid & 63;
  const int wave  = tid >> 6;
  const int col16 = lane & 15;
  const int kq    = lane >> 4;
  const int part  = blockIdx.x >> 7;    // slow dim: 0..3
  const int tg    = blockIdx.x & 127;   // XCD = tg % 8 for all parts of tg
  const int tok0  = tg * 128 + wave * 16;

  const float* aP0 = hidden + (size_t)(tok0 + col16) * HDIM + part * KPW + kq * 8;
  // staging role: wave -> (ksub, nt-quarter)
  const int snt  = wave & 3;
  const int ksub = wave >> 2;
  const float* gB = gate + (size_t)(snt * 16 + col16) * HDIM
                         + part * KPW + ksub * 32 + kq * 8;
  int4* const sdst = &bbuf[0][ksub * 768 + snt * 3 * 64 + lane];  // +CHU buf1

  f32x4 acc0[4];
#pragma unroll
  for (int nt = 0; nt < 4; ++nt) acc0[nt] = (f32x4){0.f, 0.f, 0.f, 0.f};

  // ---- prologue: split chunk 0 into buf0; prefetch gate chunk 1; A(0,sub0) --
  {
    int4 h, m, l;
    split8(L(gB), L(gB + 4), h, m, l);
    sdst[0] = h; sdst[64] = m; sdst[128] = l;
  }
  float4 g0 = L(gB + 64), g1 = L(gB + 68);
  float4 a00 = L(aP0), a01 = L(aP0 + 4);
  __syncthreads();                       // buf0 + A(0,sub0) ready

#pragma unroll 1
  for (int c = 0; c < NCHK; ++c) {
    const int cur = c & 1;
    const int kb  = c * 64;
    // issue sub1 A loads (consumed after MFMA sub0)
    float4 b00 = L(aP0 + kb + 32), b01 = L(aP0 + kb + 36);

    int4 h4, m4, l4;
    split8(a00, a01, h4, m4, l4);
    const bf16x8 a0h = asbf(h4), a0m = asbf(m4), a0l = asbf(l4);
#pragma unroll
    for (int nt = 0; nt < 4; ++nt) {
      const bf16x8 bh = asbf(bbuf[cur][(nt * 3 + 0) * 64 + lane]);
      const bf16x8 bm = asbf(bbuf[cur][(nt * 3 + 1) * 64 + lane]);
      const bf16x8 bl = asbf(bbuf[cur][(nt * 3 + 2) * 64 + lane]);
      MFMA6(acc0[nt], a0h, a0m, a0l, bh, bm, bl);
    }
    // issue next-chunk sub0 A loads (covered by MFMA sub1 + barrier)
    if (c + 1 < NCHK) {
      a00 = L(aP0 + kb + 64); a01 = L(aP0 + kb + 68);
    }
    // MFMA sub1
    split8(b00, b01, h4, m4, l4);
    const bf16x8 c0h = asbf(h4), c0m = asbf(m4), c0l = asbf(l4);
#pragma unroll
    for (int nt = 0; nt < 4; ++nt) {
      const bf16x8 bh = asbf(bbuf[cur][768 + (nt * 3 + 0) * 64 + lane]);
      const bf16x8 bm = asbf(bbuf[cur][768 + (nt * 3 + 1) * 64 + lane]);
      const bf16x8 bl = asbf(bbuf[cur][768 + (nt * 3 + 2) * 64 + lane]);
      MFMA6(acc0[nt], c0h, c0m, c0l, bh, bm, bl);
    }
    // write-late: split gate(c+1) from regs, then issue gate(c+2) loads
    if (c + 1 < NCHK) {
      int4 h, m, l;
      split8(g0, g1, h, m, l);
      int4* d = sdst + (cur ^ 1) * CHU;
      d[0] = h; d[64] = m; d[128] = l;
      if (c + 2 < NCHK) {
        g0 = L(gB + kb + 128); g1 = L(gB + kb + 132);
      }
    }
    __syncthreads();                     // buf[cur] consumed; c+1 planes landed
  }

  // partials[part][tok][e] — stays in this token group's XCD L2
  float* prow = pw + (size_t)part * TOKENS * 64;
#pragma unroll
  for (int nt = 0; nt < 4; ++nt)
#pragma unroll
    for (int r = 0; r < 4; ++r) {
      const int tok = tok0 + kq * 4 + r;
      prow[(size_t)tok * 64 + nt * 16 + col16] = acc0[nt][r];
    }
}

// Block b serves tokens whose pw lives on XCD b&7 (same-XCD L2 reads).
// Per-expert stats -> plain per-block stores in pb[b][128] (no atomics).
__global__ __launch_bounds__(256, 4)
void router_top2_kernel(const float* __restrict__ pw,
                        float* __restrict__ out,
                        float* __restrict__ pb) {
  __shared__ float red[2][4][4][16];     // [psum/cnt][wave][slice][16]

  const int tid  = threadIdx.x;
  const int lane = tid & 63, wave = tid >> 6;
  const int b    = blockIdx.x;
  const int xcd  = b & 7, j = b >> 3;
  const int tok0 = (xcd + 8 * (j >> 1)) * 128 + (j & 1) * 64;
  const int tok  = tok0 + wave * 16 + (lane >> 2);
  const int sl   = lane & 3;             // expert slice: e in [sl*16, sl*16+16)

  f32x4 s[4];
#pragma unroll
  for (int q = 0; q < 4; ++q) s[q] = (f32x4){0.f, 0.f, 0.f, 0.f};
#pragma unroll
  for (int p = 0; p < NPARTS; ++p) {
    const float* bp = pw + ((size_t)p * TOKENS + tok) * 64 + sl * 16;
#pragma unroll
    for (int q = 0; q < 4; ++q) {
      const float4 v = L(bp + q * 4);
      s[q][0] += v.x; s[q][1] += v.y; s[q][2] += v.z; s[q][3] += v.w;
    }
  }

  // in-lane top-2 over 16 experts, ascending index (tie -> lower)
  float v1 = s[0][0]; int i1 = sl * 16;
  float v2 = -3.4e38f; int i2 = 1 << 30;
#pragma unroll
  for (int q = 0; q < 4; ++q)
#pragma unroll
    for (int jj = 0; jj < 4; ++jj) {
      if (q == 0 && jj == 0) continue;
      const float v = s[q][jj]; const int ix = sl * 16 + q * 4 + jj;
      if (v > v1)      { v2 = v1; i2 = i1; v1 = v; i1 = ix; }
      else if (v > v2) { v2 = v;  i2 = ix; }
    }
  // merge across the 4 slice-lanes of this token
#pragma unroll
  for (int m = 1; m < 4; m <<= 1) {
    const float ov1 = __shfl_xor(v1, m, 64); const int oi1 = __shfl_xor(i1, m, 64);
    const float ov2 = __shfl_xor(v2, m, 64); const int oi2 = __shfl_xor(i2, m, 64);
    const bool  ob  = (ov1 > v1) || (ov1 == v1 && oi1 < i1);
    const float lv  = ob ? v1  : ov1;  const int li = ob ? i1  : oi1;
    const float rv  = ob ? ov2 : v2;   const int ri = ob ? oi2 : i2;
    v1 = ob ? ov1 : v1; i1 = ob ? oi1 : i1;
    const bool  ab  = (lv > rv) || (lv == rv && li < ri);
    v2 = ab ? lv : rv;  i2 = ab ? li : ri;
  }
  // full softmax over 64 experts (v1 = true max in all 4 lanes)
  float el[16]; float ls = 0.f;
#pragma unroll
  for (int q = 0; q < 4; ++q)
#pragma unroll
    for (int jj = 0; jj < 4; ++jj) { el[q*4+jj] = expf(s[q][jj] - v1); ls += el[q*4+jj]; }
#pragma unroll
  for (int m = 1; m < 4; m <<= 1) ls += __shfl_xor(ls, m, 64);
  const float inv = 1.f / ls;

  float psum[16], cnt[16];
#pragma unroll
  for (int jj = 0; jj < 16; ++jj) {
    psum[jj] = el[jj] * inv;
    const int ix = sl * 16 + jj;
    cnt[jj] = (float)((i1 == ix) + (i2 == ix));
  }

  if (sl == 0) {
    const float e2 = expf(v2 - v1);
    const float w1 = 1.f / (1.f + e2);
    out[tok * 2 + 0] = w1;
    out[tok * 2 + 1] = e2 * w1;
    out[(size_t)TOKENS * 2 + tok * 2 + 0] = (float)i1;
    out[(size_t)TOKENS * 2 + tok * 2 + 1] = (float)i2;
  }

  // per-expert stats: reduce over the 16 tokens of this wave (stride-4 lanes)
#pragma unroll
  for (int m = 4; m < 64; m <<= 1)
#pragma unroll
    for (int jj = 0; jj < 16; ++jj) {
      psum[jj] += __shfl_xor(psum[jj], m, 64);
      cnt[jj]  += __shfl_xor(cnt[jj], m, 64);
    }
  if (lane < 4) {
#pragma unroll
    for (int jj = 0; jj < 16; ++jj) {
      red[0][wave][sl][jj] = psum[jj];
      red[1][wave][sl][jj] = cnt[jj];
    }
  }
  __syncthreads();
  if (tid < 64) {
    const int sl2 = tid >> 4, j2 = tid & 15;
    float ps = 0.f, cs = 0.f;
#pragma unroll
    for (int w = 0; w < 4; ++w) { ps += red[0][w][sl2][j2]; cs += red[1][w][sl2][j2]; }
    pb[(size_t)b * 128 + sl2 * 16 + j2]      = ps;   // plain stores
    pb[(size_t)b * 128 + 64 + sl2 * 16 + j2] = cs;
  }
}

__global__ void router_loss_kernel(const float* __restrict__ pb,
                                   float* __restrict__ out) {
  __shared__ float red[2][4][64];
  const int tid = threadIdx.x;          // 256
  const int e = tid & 63, q = tid >> 6; // q = block-quarter
  float ps = 0.f, cs = 0.f;
#pragma unroll 4
  for (int b = q * 64; b < q * 64 + 64; ++b) {
    ps += pb[(size_t)b * 128 + e];
    cs += pb[(size_t)b * 128 + 64 + e];
  }
  red[0][q][e] = ps; red[1][q][e] = cs;
  __syncthreads();
  if (tid < 64) {
    const float P = red[0][0][tid] + red[0][1][tid] + red[0][2][tid] + red[0][3][tid];
    const float C = red[1][0][tid] + red[1][1][tid] + red[1][2][tid] + red[1][3][tid];
    float term = P * C;
#pragma unroll
    for (int m = 1; m < 64; m <<= 1) term += __shfl_xor(term, m, 64);
    if (tid == 0) {
      const float invN = 1.f / (float)TOKENS;
      out[(size_t)TOKENS * 4] = 0.01f * 64.f * term * invN * invN;
    }
  }
}

extern "C" void kernel_launch(void* const* d_in, const int* in_sizes, int n_in,
                              void* d_out, int out_size, void* d_ws, size_t ws_size,
                              hipStream_t stream) {
  const float* hidden = (const float*)d_in[0];  // [4,4096,4096] f32
  const float* gate   = (const float*)d_in[1];  // [64,4096] f32
  float* out   = (float*)d_out;                 // 32768 w + 32768 idx + 1 loss

  float* pb = (float*)d_ws;                                // 128 KB block partials
  float* pw = (float*)((char*)d_ws + 131072);              // 16.8 MB partials

  router_gemm_kernel<<<NPARTS * (TOKENS / 128), 512, 0, stream>>>(hidden, gate, pw);
  router_top2_kernel<<<TOKENS / 64, 256, 0, stream>>>(pw, out, pb);
  router_loss_kernel<<<1, 256, 0, stream>>>(pb, out);
}